// Round 1
// baseline (660.796 us; speedup 1.0000x reference)
//
#include <hip/hip_runtime.h>

#define M 8192

// ---------------------------------------------------------------------------
// Kernel 1: fused q/k/v GEMV.  y = W @ x + b for W in {Wq, Wk, Wv}.
// One wave (64 lanes) per output row; 4 waves / 256-thread block.
// x (32 KB) staged in LDS once per block; W rows streamed as float4.
// 24576 rows -> 6144 blocks.  HBM-bound: 805 MB of W traffic.
// ---------------------------------------------------------------------------
__global__ __launch_bounds__(256) void qkv_gemv_kernel(
    const float* __restrict__ x,
    const float* __restrict__ Wq, const float* __restrict__ bq,
    const float* __restrict__ Wk, const float* __restrict__ bk,
    const float* __restrict__ Wv, const float* __restrict__ bv,
    float* __restrict__ qkv)
{
    __shared__ float4 xs4[M / 4];

    const float4* x4 = (const float4*)x;
    for (int t = threadIdx.x; t < M / 4; t += 256) xs4[t] = x4[t];
    __syncthreads();

    const int wave = threadIdx.x >> 6;
    const int lane = threadIdx.x & 63;
    const int R    = blockIdx.x * 4 + wave;   // 0 .. 24575 (global row id)
    const int m    = R >> 13;                 // 0=q, 1=k, 2=v (8192 rows each; blocks never straddle)
    const int row  = R & (M - 1);

    const float* W = (m == 0) ? Wq : (m == 1) ? Wk : Wv;
    const float* b = (m == 0) ? bq : (m == 1) ? bk : bv;
    const float4* Wr = (const float4*)(W + (size_t)row * M);

    float ax = 0.f, ay = 0.f, az = 0.f, aw = 0.f;
#pragma unroll 8
    for (int j = lane; j < M / 4; j += 64) {
        float4 w  = Wr[j];
        float4 xv = xs4[j];
        ax = fmaf(w.x, xv.x, ax);
        ay = fmaf(w.y, xv.y, ay);
        az = fmaf(w.z, xv.z, az);
        aw = fmaf(w.w, xv.w, aw);
    }
    float s = (ax + ay) + (az + aw);
#pragma unroll
    for (int off = 32; off > 0; off >>= 1) s += __shfl_down(s, off, 64);
    if (lane == 0) qkv[R] = s + b[row];
}

// ---------------------------------------------------------------------------
// Kernel 2: out[i] = sum_j exp(s_i*k_j) * v_j / sum_j exp(s_i*k_j),
// with s_i = q[i]/32.  Scores bounded (|s*k| < ~2) -> no max-subtraction.
// k (pre-scaled by log2(e)/32) and v staged in LDS (64 KB).
// 1024 threads = 16 waves per block; one i per wave; 512 blocks.
// ---------------------------------------------------------------------------
__global__ __launch_bounds__(1024) void attn_kernel(
    const float* __restrict__ qkv, float* __restrict__ out)
{
    __shared__ float4 kl4[M / 4];
    __shared__ float4 vs4[M / 4];

    const float*  q  = qkv;
    const float4* k4 = (const float4*)(qkv + M);
    const float4* v4 = (const float4*)(qkv + 2 * M);
    const float c = 1.44269504088896340736f / 32.0f;  // log2(e)/sqrt(HEAD_DIM)

    for (int t = threadIdx.x; t < M / 4; t += 1024) {
        float4 kk = k4[t];
        float4 vv = v4[t];
        kl4[t] = make_float4(kk.x * c, kk.y * c, kk.z * c, kk.w * c);
        vs4[t] = vv;
    }
    __syncthreads();

    const int wave = threadIdx.x >> 6;
    const int lane = threadIdx.x & 63;
    const int i    = blockIdx.x * 16 + wave;  // 512 blocks * 16 waves = 8192 rows

    const float s = q[i];
    float num = 0.f, den = 0.f;
#pragma unroll 2
    for (int j = lane; j < M / 4; j += 64) {
        float4 kk = kl4[j];
        float4 vv = vs4[j];
        float e0 = __builtin_amdgcn_exp2f(s * kk.x);
        float e1 = __builtin_amdgcn_exp2f(s * kk.y);
        float e2 = __builtin_amdgcn_exp2f(s * kk.z);
        float e3 = __builtin_amdgcn_exp2f(s * kk.w);
        num = fmaf(e0, vv.x, num);
        num = fmaf(e1, vv.y, num);
        num = fmaf(e2, vv.z, num);
        num = fmaf(e3, vv.w, num);
        den += (e0 + e1) + (e2 + e3);
    }
#pragma unroll
    for (int off = 32; off > 0; off >>= 1) {
        num += __shfl_down(num, off, 64);
        den += __shfl_down(den, off, 64);
    }
    if (lane == 0) out[i] = num / den;
}

extern "C" void kernel_launch(void* const* d_in, const int* in_sizes, int n_in,
                              void* d_out, int out_size, void* d_ws, size_t ws_size,
                              hipStream_t stream) {
    const float* x  = (const float*)d_in[0];
    const float* Wq = (const float*)d_in[1];
    const float* bq = (const float*)d_in[2];
    const float* Wk = (const float*)d_in[3];
    const float* bk = (const float*)d_in[4];
    const float* Wv = (const float*)d_in[5];
    const float* bv = (const float*)d_in[6];
    float* out = (float*)d_out;
    float* qkv = (float*)d_ws;  // [3*M] floats: q | k | v  (96 KB of workspace)

    qkv_gemv_kernel<<<dim3(3 * M / 4), dim3(256), 0, stream>>>(
        x, Wq, bq, Wk, bk, Wv, bv, qkv);
    attn_kernel<<<dim3(M / 16), dim3(1024), 0, stream>>>(qkv, out);
}